// Round 4
// baseline (780.474 us; speedup 1.0000x reference)
//
#include <hip/hip_runtime.h>
#include <hip/hip_cooperative_groups.h>
#include <hip/hip_bf16.h>
#include <stdint.h>
#include <stddef.h>

namespace cg = cooperative_groups;

// Problem constants (match reference)
#define NB 16       // genes
#define NS 4096     // splice sites per gene
#define NSA 4098    // augmented sites (incl. gene_start, gene_end)
#define NC 512      // channels per site rep
#define NJ 4096     // junctions per gene
#define NT 64       // transcripts per gene
#define NKJ 32      // junctions per transcript
#define KD 1024     // 2*NC = MLP in/hidden dim
#define NM (NB * NJ)  // 65536 rows

typedef __hip_bfloat16 bf16;
typedef __attribute__((ext_vector_type(8))) short bf16x8;  // 8 bf16 = 4 VGPRs
typedef __attribute__((ext_vector_type(4))) float f32x4;

// GEMM tile geometry: BM=128 x BN=128 x BK=64, 4 waves (2x2),
// 4x4 16x16x32 MFMA per wave. LDS 16B-granule XOR swizzle: logical
// (row m, granule g) stored at slot m*8 + (g ^ (m&7)).
#define BM 128
#define BN 128
#define BK 64

// async global->LDS, 16B per lane. Global address is PER-LANE (gather ok);
// LDS dest = wave-uniform base + lane*16.
__device__ __forceinline__ void gload_lds16(const bf16* g, bf16* l) {
  __builtin_amdgcn_global_load_lds(
      (const __attribute__((address_space(1))) void*)g,
      (__attribute__((address_space(3))) void*)l, 16, 0, 0);
}

// ---------------------------------------------------------------------------
// One cooperative persistent kernel; phases separated by grid.sync().
// grid = min(1024, occupancy*CUs) blocks x 256 threads, gridDim-stride loops.
__global__ __launch_bounds__(256, 4) void mega_kernel(
    const float* __restrict__ ssr, const int* __restrict__ don,
    const int* __restrict__ acc, const int* __restrict__ tj,
    const float* __restrict__ W1, const float* __restrict__ b1,
    const float* __restrict__ W2, const float* __restrict__ b2,
    const float* __restrict__ W3, const float* __restrict__ b3,
    const float* __restrict__ gstart, const float* __restrict__ gend,
    const float* __restrict__ refp, float* __restrict__ out,
    bf16* __restrict__ W1t, bf16* __restrict__ W2t,
    bf16* __restrict__ aug, bf16* __restrict__ H1,
    float* __restrict__ pot) {
  cg::grid_group grid = cg::this_grid();
  __shared__ __align__(16) bf16 As[BM * BK];
  __shared__ __align__(16) bf16 Bs[BN * BK];
  const int bid = blockIdx.x;
  const int tid = threadIdx.x;
  const int G = gridDim.x;
  const int wave = tid >> 6;
  const int lane = tid & 63;
  const int wm = wave & 1;
  const int wn = wave >> 1;
  const int q = lane >> 4;
  const int rr = lane & 15;

  // staging descriptors: LDS slot L covers logical (row m, granule g)
  int mm[4], gg[4];
#pragma unroll
  for (int i = 0; i < 4; i++) {
    int L = wave * 256 + i * 64 + lane;
    int m = L >> 3;
    int g = (L & 7) ^ (m & 7);
    mm[i] = m; gg[i] = g;
  }

  // ===== phase 0a: weight transpose+cast (2048 virtual 32x32 tiles) =====
  {
    bf16(*tile)[33] = (bf16(*)[33])As;  // 2.1 KB, reuses As
    const int c = tid & 31;
    const int r0 = tid >> 5;  // 0..7
    for (int vb = bid; vb < 2048; vb += G) {
      const float* W = (vb >= 1024) ? W2 : W1;
      bf16* Wt = (vb >= 1024) ? W2t : W1t;
      const int pos = vb & 1023;
      const int n0 = (pos & 31) * 32;
      const int k0 = (pos >> 5) * 32;
      __syncthreads();  // protect tile reuse across vb iterations
#pragma unroll
      for (int i = 0; i < 4; i++) {
        int r = r0 + i * 8;
        tile[r][c] = __float2bfloat16(W[(size_t)(k0 + r) * KD + (n0 + c)]);
      }
      __syncthreads();
#pragma unroll
      for (int i = 0; i < 4; i++) {
        int r = r0 + i * 8;
        Wt[(size_t)(n0 + r) * KD + (k0 + c)] = tile[c][r];
      }
    }
  }
  // ===== phase 0b: build augmented bf16 site table (4 rows / virtual blk) ==
  for (int vb = bid; vb < (NB * NSA) / 4; vb += G) {
    const int row = vb * 4 + (tid >> 6);
    const int g = tid & 63;
    const int b = row / NSA;
    const int s = row - b * NSA;
    const float* src;
    if (s < NS)       src = ssr + ((size_t)b * NS + s) * NC + g * 8;
    else if (s == NS) src = gstart + g * 8;
    else              src = gend + g * 8;
    f32x4 f0 = *(const f32x4*)(src);
    f32x4 f1 = *(const f32x4*)(src + 4);
    union { bf16x8 v; bf16 e[8]; } u;
    u.e[0] = __float2bfloat16(f0.x); u.e[1] = __float2bfloat16(f0.y);
    u.e[2] = __float2bfloat16(f0.z); u.e[3] = __float2bfloat16(f0.w);
    u.e[4] = __float2bfloat16(f1.x); u.e[5] = __float2bfloat16(f1.y);
    u.e[6] = __float2bfloat16(f1.z); u.e[7] = __float2bfloat16(f1.w);
    *(bf16x8*)(aug + (size_t)row * NC + g * 8) = u.v;
  }
  // ===== phase 0c: zero pot =====
  for (int i = bid * 256 + tid; i < NM; i += G * 256) pot[i] = 0.f;

  grid.sync();

  // ===== phase 1: gemm1 with fused gather, 4096 tiles =====
  // A row r = concat(aug[don[r]], aug[acc[r]]); C = relu(A@W1t^T+b1) -> H1
  for (int vt = bid; vt < 4096; vt += G) {
    const int row0 = (vt >> 3) * BM;
    const int col0 = (vt & 7) * BN;
    const bf16* dp[4];
    const bf16* ap[4];
#pragma unroll
    for (int i = 0; i < 4; i++) {
      const int r = row0 + mm[i];
      const int b = r >> 12;
      dp[i] = aug + ((size_t)b * NSA + don[r]) * NC;
      ap[i] = aug + ((size_t)b * NSA + acc[r]) * NC;
    }
    f32x4 acc4[4][4] = {};
    for (int kt = 0; kt < KD / BK; ++kt) {
      const int ko = (kt & 7) * BK;
#pragma unroll
      for (int i = 0; i < 4; i++) {
        const bf16* abase = (kt < 8) ? dp[i] : ap[i];
        gload_lds16(abase + ko + gg[i] * 8,
                    As + (size_t)(wave * 256 + i * 64) * 8);
        gload_lds16(W1t + ((size_t)(col0 + mm[i]) * KD + kt * BK + gg[i] * 8),
                    Bs + (size_t)(wave * 256 + i * 64) * 8);
      }
      __syncthreads();
#pragma unroll
      for (int kk = 0; kk < 2; ++kk) {
        bf16x8 afr[4], bfr[4];
        const int g = kk * 4 + q;
#pragma unroll
        for (int mt = 0; mt < 4; mt++) {
          int m = wm * 64 + mt * 16 + rr;
          afr[mt] = *(const bf16x8*)(As + (m * 8 + (g ^ (m & 7))) * 8);
        }
#pragma unroll
        for (int nt = 0; nt < 4; nt++) {
          int n = wn * 64 + nt * 16 + rr;
          bfr[nt] = *(const bf16x8*)(Bs + (n * 8 + (g ^ (n & 7))) * 8);
        }
#pragma unroll
        for (int mt = 0; mt < 4; mt++)
#pragma unroll
          for (int nt = 0; nt < 4; nt++)
            acc4[mt][nt] = __builtin_amdgcn_mfma_f32_16x16x32_bf16(
                afr[mt], bfr[nt], acc4[mt][nt], 0, 0, 0);
      }
      __syncthreads();
    }
    // epilogue: C/D layout col = lane&15, row = quad*4 + reg
#pragma unroll
    for (int nt = 0; nt < 4; nt++) {
      const int col = col0 + wn * 64 + nt * 16 + rr;
      const float bv = b1[col];
#pragma unroll
      for (int mt = 0; mt < 4; mt++) {
        const int rbase = row0 + wm * 64 + mt * 16 + q * 4;
#pragma unroll
        for (int rg = 0; rg < 4; rg++) {
          float v = fmaxf(acc4[mt][nt][rg] + bv, 0.f);
          H1[(size_t)(rbase + rg) * KD + col] = __float2bfloat16(v);
        }
      }
    }
  }

  grid.sync();

  // ===== phase 2: gemm2, fused w3 GEMV epilogue -> pot (atomicAdd) =====
  for (int vt = bid; vt < 4096; vt += G) {
    const int row0 = (vt >> 3) * BM;
    const int col0 = (vt & 7) * BN;
    f32x4 acc4[4][4] = {};
    for (int kt = 0; kt < KD / BK; ++kt) {
#pragma unroll
      for (int i = 0; i < 4; i++) {
        gload_lds16(H1 + ((size_t)(row0 + mm[i]) * KD + kt * BK + gg[i] * 8),
                    As + (size_t)(wave * 256 + i * 64) * 8);
        gload_lds16(W2t + ((size_t)(col0 + mm[i]) * KD + kt * BK + gg[i] * 8),
                    Bs + (size_t)(wave * 256 + i * 64) * 8);
      }
      __syncthreads();
#pragma unroll
      for (int kk = 0; kk < 2; ++kk) {
        bf16x8 afr[4], bfr[4];
        const int g = kk * 4 + q;
#pragma unroll
        for (int mt = 0; mt < 4; mt++) {
          int m = wm * 64 + mt * 16 + rr;
          afr[mt] = *(const bf16x8*)(As + (m * 8 + (g ^ (m & 7))) * 8);
        }
#pragma unroll
        for (int nt = 0; nt < 4; nt++) {
          int n = wn * 64 + nt * 16 + rr;
          bfr[nt] = *(const bf16x8*)(Bs + (n * 8 + (g ^ (n & 7))) * 8);
        }
#pragma unroll
        for (int mt = 0; mt < 4; mt++)
#pragma unroll
          for (int nt = 0; nt < 4; nt++)
            acc4[mt][nt] = __builtin_amdgcn_mfma_f32_16x16x32_bf16(
                afr[mt], bfr[nt], acc4[mt][nt], 0, 0, 0);
      }
      __syncthreads();
    }
    float bv[4], wv[4];
#pragma unroll
    for (int nt = 0; nt < 4; nt++) {
      const int col = col0 + wn * 64 + nt * 16 + rr;
      bv[nt] = b2[col];
      wv[nt] = W3[col];
    }
#pragma unroll
    for (int mt = 0; mt < 4; mt++) {
#pragma unroll
      for (int rg = 0; rg < 4; rg++) {
        float s = 0.f;
#pragma unroll
        for (int nt = 0; nt < 4; nt++)
          s += fmaxf(acc4[mt][nt][rg] + bv[nt], 0.f) * wv[nt];
        s += __shfl_xor(s, 1);
        s += __shfl_xor(s, 2);
        s += __shfl_xor(s, 4);
        s += __shfl_xor(s, 8);
        if (rr == 0) {
          int row = row0 + wm * 64 + mt * 16 + q * 4 + rg;
          atomicAdd(&pot[row], s);
        }
      }
    }
  }

  grid.sync();

  // ===== phase 3: per-gene transcript sum + softmax over T+1 =====
  if (bid < NB && tid < 64) {
    const int b = bid;
    const int t = tid;
    const int* tjb = tj + ((size_t)b * NT + t) * NKJ;
    float s = 0.f;
#pragma unroll
    for (int k = 0; k < NKJ; k++) s += pot[b * NJ + tjb[k]];
    s += (float)NKJ * b3[0];
    const float ref = refp[0];
    float m = fmaxf(s, ref);
#pragma unroll
    for (int o = 1; o < 64; o <<= 1) m = fmaxf(m, __shfl_xor(m, o));
    const float e = expf(s - m);
    float denom = e;
#pragma unroll
    for (int o = 1; o < 64; o <<= 1) denom += __shfl_xor(denom, o);
    const float eref = expf(ref - m);
    denom += eref;
    out[b * (NT + 1) + t] = e / denom;
    if (t == 0) out[b * (NT + 1) + NT] = eref / denom;
  }
}

// ---------------------------------------------------------------------------
extern "C" void kernel_launch(void* const* d_in, const int* in_sizes, int n_in,
                              void* d_out, int out_size, void* d_ws,
                              size_t ws_size, hipStream_t stream) {
  const float* ssr    = (const float*)d_in[0];   // [16,4096,512]
  const int*   don    = (const int*)d_in[1];     // [16,4096]
  const int*   acc    = (const int*)d_in[2];     // [16,4096]
  const int*   tj     = (const int*)d_in[3];     // [16,64,32]
  const float* W1     = (const float*)d_in[4];   // [1024,1024]
  const float* b1     = (const float*)d_in[5];   // [1024]
  const float* W2     = (const float*)d_in[6];   // [1024,1024]
  const float* b2     = (const float*)d_in[7];   // [1024]
  const float* W3     = (const float*)d_in[8];   // [1024,1]
  const float* b3     = (const float*)d_in[9];   // [1]
  const float* gstart = (const float*)d_in[10];  // [512]
  const float* gend   = (const float*)d_in[11];  // [512]
  const float* refp   = (const float*)d_in[12];  // [1]
  float* out = (float*)d_out;                    // [16,65]

  // workspace layout (~200 MiB)
  char* ws = (char*)d_ws;
  bf16* W1t = (bf16*)ws;                 ws += (size_t)KD * KD * 2;
  bf16* W2t = (bf16*)ws;                 ws += (size_t)KD * KD * 2;
  bf16* aug = (bf16*)ws;                 ws += (size_t)NB * NSA * NC * 2;
  bf16* H1  = (bf16*)ws;                 ws += (size_t)NM * KD * 2;
  float* pot = (float*)ws;               ws += (size_t)NM * 4;

  // co-resident grid: target 4 blocks/CU x 256 CUs = 1024; clamp by occupancy
  int maxb = 0;
  hipOccupancyMaxActiveBlocksPerMultiprocessor(&maxb, (const void*)mega_kernel,
                                               256, 0);
  if (maxb < 1) maxb = 1;
  int nblk = maxb * 256;          // 256 CUs on MI355X
  if (nblk > 1024) nblk = 1024;

  void* args[] = {&ssr, &don, &acc, &tj, &W1, &b1, &W2, &b2, &W3, &b3,
                  &gstart, &gend, &refp, &out, &W1t, &W2t, &aug, &H1, &pot};
  hipLaunchCooperativeKernel((void*)mega_kernel, dim3(nblk), dim3(256), args,
                             0, stream);
}

// Round 6
// 480.824 us; speedup vs baseline: 1.6232x; 1.6232x over previous
//
#include <hip/hip_runtime.h>
#include <hip/hip_bf16.h>
#include <stdint.h>
#include <stddef.h>

// Problem constants (match reference)
#define NB 16       // genes
#define NS 4096     // splice sites per gene
#define NSA 4098    // augmented sites (incl. gene_start, gene_end)
#define NC 512      // channels per site rep
#define NJ 4096     // junctions per gene
#define NT 64       // transcripts per gene
#define NKJ 32      // junctions per transcript
#define KD 1024     // 2*NC = MLP in/hidden dim
#define NM (NB * NJ)  // 65536 rows

// prep kernel block ranges
#define PREP_W_BLKS 2048                    // weight transpose tiles
#define PREP_AUG_BLKS ((NB * NSA) / 4)      // 16392: aug rows / 4
#define PREP_POT_BLKS 64                    // pot zeroing

typedef __hip_bfloat16 bf16;
typedef __attribute__((ext_vector_type(8))) short bf16x8;  // 8 bf16 = 4 VGPRs
typedef __attribute__((ext_vector_type(4))) float f32x4;

// GEMM tile geometry: BM=128 x BN=128 x BK=64, 4 waves (2x2),
// 4x4 16x16x32 MFMA per wave. LDS 16B-granule XOR swizzle: logical
// (row m, granule g) stored at slot m*8 + (g ^ (m&7)).
#define BM 128
#define BN 128
#define BK 64

// async global->LDS, 16B per lane. Global address is PER-LANE (gather ok);
// LDS dest = wave-uniform base + lane*16.
__device__ __forceinline__ void gload_lds16(const bf16* g, bf16* l) {
  __builtin_amdgcn_global_load_lds(
      (const __attribute__((address_space(1))) void*)g,
      (__attribute__((address_space(3))) void*)l, 16, 0, 0);
}

// XCD-aware tile swizzle: HW round-robins blockIdx%8 across the 8 XCDs.
// Make the 8 col-blocks that share one 128-row A-stripe land on ONE XCD:
// bid = hi*64 + c*8 + lo  ->  row_idx = hi*8+lo (0..511), col_idx = c (0..7).
__device__ __forceinline__ void tile_from_bid(int bid, int& row0, int& col0) {
  const int row_idx = ((bid >> 6) << 3) | (bid & 7);  // 0..511
  const int col_idx = (bid >> 3) & 7;                 // 0..7
  row0 = row_idx * BM;
  col0 = col_idx * BN;
}

// ---------------------------------------------------------------------------
// Fused prep kernel, disjoint block ranges:
//   [0, 2048)               : W1/W2 transpose+cast 32x32 tiles -> W1t/W2t
//   [2048, 2048+16392)      : augmented bf16 site table (4 rows/block)
//   [+16392, +16392+64)     : zero pot
__global__ void prep_kernel(const float* __restrict__ W1,
                            bf16* __restrict__ W1t,
                            const float* __restrict__ W2,
                            bf16* __restrict__ W2t,
                            const float* __restrict__ ssr,
                            const float* __restrict__ gstart,
                            const float* __restrict__ gend,
                            bf16* __restrict__ aug,
                            float* __restrict__ pot) {
  const int bid = blockIdx.x;
  const int tid = threadIdx.x;
  if (bid < PREP_W_BLKS) {
    // ---- weight transpose+cast ----
    __shared__ bf16 tile[32][33];
    const float* W = (bid >= 1024) ? W2 : W1;
    bf16* Wt = (bid >= 1024) ? W2t : W1t;
    const int pos = bid & 1023;
    const int n0 = (pos & 31) * 32;
    const int k0 = (pos >> 5) * 32;
    const int c = tid & 31;
    const int r0 = tid >> 5;  // 0..7
#pragma unroll
    for (int i = 0; i < 4; i++) {
      int r = r0 + i * 8;
      tile[r][c] = __float2bfloat16(W[(size_t)(k0 + r) * KD + (n0 + c)]);
    }
    __syncthreads();
#pragma unroll
    for (int i = 0; i < 4; i++) {
      int r = r0 + i * 8;  // n-row of output
      Wt[(size_t)(n0 + r) * KD + (k0 + c)] = tile[c][r];
    }
  } else if (bid < PREP_W_BLKS + PREP_AUG_BLKS) {
    // ---- aug table: 4 rows per block, one wave per row, dense 16B loads ----
    const int row = (bid - PREP_W_BLKS) * 4 + (tid >> 6);  // 0..NB*NSA-1
    const int i = tid & 63;                                 // lane
    const int b = row / NSA;
    const int s = row - b * NSA;
    const float* src;
    if (s < NS)       src = ssr + ((size_t)b * NS + s) * NC;
    else if (s == NS) src = gstart;
    else              src = gend;
    f32x4 f0 = *(const f32x4*)(src + 4 * i);        // floats [4i, 4i+4)
    f32x4 f1 = *(const f32x4*)(src + 256 + 4 * i);  // floats [256+4i, ..)
    bf16* dst = aug + (size_t)row * NC;
    union { uint64_t u; bf16 e[4]; } a, b4;
    a.e[0] = __float2bfloat16(f0.x); a.e[1] = __float2bfloat16(f0.y);
    a.e[2] = __float2bfloat16(f0.z); a.e[3] = __float2bfloat16(f0.w);
    b4.e[0] = __float2bfloat16(f1.x); b4.e[1] = __float2bfloat16(f1.y);
    b4.e[2] = __float2bfloat16(f1.z); b4.e[3] = __float2bfloat16(f1.w);
    *(uint64_t*)(dst + 4 * i) = a.u;
    *(uint64_t*)(dst + 256 + 4 * i) = b4.u;
  } else {
    // ---- zero pot: 64 blocks x 256 threads x 4 floats = 65536 ----
    const int i = (bid - (PREP_W_BLKS + PREP_AUG_BLKS)) * 1024 + tid * 4;
    *(f32x4*)(pot + i) = (f32x4){0.f, 0.f, 0.f, 0.f};
  }
}

// ---------------------------------------------------------------------------
// GEMM1 with fused gather via async DMA: A row r = concat(aug[don[r]],
// aug[acc[r]]) in bf16; per-lane gathered global_load_lds addresses.
// C = relu(A @ W1t^T + b1) stored bf16.
__global__ __launch_bounds__(256, 2) void gemm1_gather_kernel(
    const bf16* __restrict__ aug, const int* __restrict__ don,
    const int* __restrict__ acc, const bf16* __restrict__ Bt,
    const float* __restrict__ bias, bf16* __restrict__ Cout) {
  __shared__ __align__(16) bf16 As[BM * BK];
  __shared__ __align__(16) bf16 Bs[BN * BK];
  const int tid = threadIdx.x;
  const int wave = tid >> 6;
  const int lane = tid & 63;
  int row0, col0;
  tile_from_bid(blockIdx.x, row0, col0);
  const int wm = wave & 1;
  const int wn = wave >> 1;
  const int q = lane >> 4;
  const int rr = lane & 15;

  // staging descriptors: LDS slot L covers logical (row m, granule g)
  int mm[4], gg[4];
#pragma unroll
  for (int i = 0; i < 4; i++) {
    int L = wave * 256 + i * 64 + lane;
    int m = L >> 3;
    int g = (L & 7) ^ (m & 7);
    mm[i] = m; gg[i] = g;
  }

  // per-lane gathered A row base pointers (don half / acc half of K)
  const bf16* dp[4];
  const bf16* ap[4];
#pragma unroll
  for (int i = 0; i < 4; i++) {
    const int r = row0 + mm[i];
    const int b = r >> 12;
    dp[i] = aug + ((size_t)b * NSA + don[r]) * NC;
    ap[i] = aug + ((size_t)b * NSA + acc[r]) * NC;
  }

  f32x4 acc4[4][4] = {};

  for (int kt = 0; kt < KD / BK; ++kt) {
    const int ko = (kt & 7) * BK;  // offset within the 512-wide half
#pragma unroll
    for (int i = 0; i < 4; i++) {
      const bf16* abase = (kt < 8) ? dp[i] : ap[i];
      gload_lds16(abase + ko + gg[i] * 8,
                  As + (size_t)(wave * 256 + i * 64) * 8);
      gload_lds16(Bt + ((size_t)(col0 + mm[i]) * KD + kt * BK + gg[i] * 8),
                  Bs + (size_t)(wave * 256 + i * 64) * 8);
    }
    __syncthreads();
#pragma unroll
    for (int kk = 0; kk < 2; ++kk) {
      bf16x8 afr[4], bfr[4];
      const int g = kk * 4 + q;
#pragma unroll
      for (int mt = 0; mt < 4; mt++) {
        int m = wm * 64 + mt * 16 + rr;
        afr[mt] = *(const bf16x8*)(As + (m * 8 + (g ^ (m & 7))) * 8);
      }
#pragma unroll
      for (int nt = 0; nt < 4; nt++) {
        int n = wn * 64 + nt * 16 + rr;
        bfr[nt] = *(const bf16x8*)(Bs + (n * 8 + (g ^ (n & 7))) * 8);
      }
#pragma unroll
      for (int mt = 0; mt < 4; mt++)
#pragma unroll
        for (int nt = 0; nt < 4; nt++)
          acc4[mt][nt] = __builtin_amdgcn_mfma_f32_16x16x32_bf16(
              afr[mt], bfr[nt], acc4[mt][nt], 0, 0, 0);
    }
    __syncthreads();
  }

  // Epilogue. C/D layout: col = lane&15, row = quad*4 + reg
#pragma unroll
  for (int nt = 0; nt < 4; nt++) {
    const int col = col0 + wn * 64 + nt * 16 + rr;
    const float bv = bias[col];
#pragma unroll
    for (int mt = 0; mt < 4; mt++) {
      const int rbase = row0 + wm * 64 + mt * 16 + q * 4;
#pragma unroll
      for (int rg = 0; rg < 4; rg++) {
        float v = fmaxf(acc4[mt][nt][rg] + bv, 0.f);
        Cout[(size_t)(rbase + rg) * KD + col] = __float2bfloat16(v);
      }
    }
  }
}

// ---------------------------------------------------------------------------
// GEMM2: pot contribution = relu(H1 @ W2t^T + b2) @ w3, atomicAdd per row.
__global__ __launch_bounds__(256, 2) void gemm2_kernel(
    const bf16* __restrict__ A, const bf16* __restrict__ Bt,
    const float* __restrict__ bias, const float* __restrict__ w3,
    float* __restrict__ pot) {
  __shared__ __align__(16) bf16 As[BM * BK];
  __shared__ __align__(16) bf16 Bs[BN * BK];
  const int tid = threadIdx.x;
  const int wave = tid >> 6;
  const int lane = tid & 63;
  int row0, col0;
  tile_from_bid(blockIdx.x, row0, col0);
  const int wm = wave & 1;
  const int wn = wave >> 1;
  const int q = lane >> 4;
  const int rr = lane & 15;

  int mm[4], gg[4];
#pragma unroll
  for (int i = 0; i < 4; i++) {
    int L = wave * 256 + i * 64 + lane;
    int m = L >> 3;
    int g = (L & 7) ^ (m & 7);
    mm[i] = m; gg[i] = g;
  }

  f32x4 acc4[4][4] = {};

  for (int kt = 0; kt < KD / BK; ++kt) {
#pragma unroll
    for (int i = 0; i < 4; i++) {
      gload_lds16(A + ((size_t)(row0 + mm[i]) * KD + kt * BK + gg[i] * 8),
                  As + (size_t)(wave * 256 + i * 64) * 8);
      gload_lds16(Bt + ((size_t)(col0 + mm[i]) * KD + kt * BK + gg[i] * 8),
                  Bs + (size_t)(wave * 256 + i * 64) * 8);
    }
    __syncthreads();
#pragma unroll
    for (int kk = 0; kk < 2; ++kk) {
      bf16x8 afr[4], bfr[4];
      const int g = kk * 4 + q;
#pragma unroll
      for (int mt = 0; mt < 4; mt++) {
        int m = wm * 64 + mt * 16 + rr;
        afr[mt] = *(const bf16x8*)(As + (m * 8 + (g ^ (m & 7))) * 8);
      }
#pragma unroll
      for (int nt = 0; nt < 4; nt++) {
        int n = wn * 64 + nt * 16 + rr;
        bfr[nt] = *(const bf16x8*)(Bs + (n * 8 + (g ^ (n & 7))) * 8);
      }
#pragma unroll
      for (int mt = 0; mt < 4; mt++)
#pragma unroll
        for (int nt = 0; nt < 4; nt++)
          acc4[mt][nt] = __builtin_amdgcn_mfma_f32_16x16x32_bf16(
              afr[mt], bfr[nt], acc4[mt][nt], 0, 0, 0);
    }
    __syncthreads();
  }

  float bv[4], wv[4];
#pragma unroll
  for (int nt = 0; nt < 4; nt++) {
    const int col = col0 + wn * 64 + nt * 16 + rr;
    bv[nt] = bias[col];
    wv[nt] = w3[col];
  }
#pragma unroll
  for (int mt = 0; mt < 4; mt++) {
#pragma unroll
    for (int rg = 0; rg < 4; rg++) {
      float s = 0.f;
#pragma unroll
      for (int nt = 0; nt < 4; nt++)
        s += fmaxf(acc4[mt][nt][rg] + bv[nt], 0.f) * wv[nt];
      s += __shfl_xor(s, 1);
      s += __shfl_xor(s, 2);
      s += __shfl_xor(s, 4);
      s += __shfl_xor(s, 8);
      if (rr == 0) {
        int row = row0 + wm * 64 + mt * 16 + q * 4 + rg;
        atomicAdd(&pot[row], s);
      }
    }
  }
}

// ---------------------------------------------------------------------------
// Per-gene transcript potential sum + softmax over T+1 entries.
__global__ void transcript_softmax_kernel(const float* __restrict__ pot,
                                          const int* __restrict__ tj,
                                          const float* __restrict__ b3,
                                          const float* __restrict__ refp,
                                          float* __restrict__ out) {
  const int b = blockIdx.x;
  const int t = threadIdx.x;  // 64 threads = 1 wave
  const int* tjb = tj + ((size_t)b * NT + t) * NKJ;
  float s = 0.f;
#pragma unroll
  for (int k = 0; k < NKJ; k++) s += pot[b * NJ + tjb[k]];
  s += (float)NKJ * b3[0];
  const float ref = refp[0];
  float m = fmaxf(s, ref);
#pragma unroll
  for (int o = 1; o < 64; o <<= 1) m = fmaxf(m, __shfl_xor(m, o));
  const float e = expf(s - m);
  float denom = e;
#pragma unroll
  for (int o = 1; o < 64; o <<= 1) denom += __shfl_xor(denom, o);
  const float eref = expf(ref - m);
  denom += eref;
  out[b * (NT + 1) + t] = e / denom;
  if (t == 0) out[b * (NT + 1) + NT] = eref / denom;
}

// ---------------------------------------------------------------------------
extern "C" void kernel_launch(void* const* d_in, const int* in_sizes, int n_in,
                              void* d_out, int out_size, void* d_ws,
                              size_t ws_size, hipStream_t stream) {
  const float* ssr    = (const float*)d_in[0];   // [16,4096,512]
  const int*   don    = (const int*)d_in[1];     // [16,4096]
  const int*   acc    = (const int*)d_in[2];     // [16,4096]
  const int*   tj     = (const int*)d_in[3];     // [16,64,32]
  const float* W1     = (const float*)d_in[4];   // [1024,1024]
  const float* b1     = (const float*)d_in[5];   // [1024]
  const float* W2     = (const float*)d_in[6];   // [1024,1024]
  const float* b2     = (const float*)d_in[7];   // [1024]
  const float* W3     = (const float*)d_in[8];   // [1024,1]
  const float* b3     = (const float*)d_in[9];   // [1]
  const float* gstart = (const float*)d_in[10];  // [512]
  const float* gend   = (const float*)d_in[11];  // [512]
  const float* refp   = (const float*)d_in[12];  // [1]
  float* out = (float*)d_out;                    // [16,65]

  // workspace layout (~200 MiB)
  char* ws = (char*)d_ws;
  bf16* W1t = (bf16*)ws;                 ws += (size_t)KD * KD * 2;
  bf16* W2t = (bf16*)ws;                 ws += (size_t)KD * KD * 2;
  bf16* aug = (bf16*)ws;                 ws += (size_t)NB * NSA * NC * 2;
  bf16* H1  = (bf16*)ws;                 ws += (size_t)NM * KD * 2;
  float* pot = (float*)ws;               ws += (size_t)NM * 4;

  prep_kernel<<<PREP_W_BLKS + PREP_AUG_BLKS + PREP_POT_BLKS, 256, 0, stream>>>(
      W1, W1t, W2, W2t, ssr, gstart, gend, aug, pot);

  gemm1_gather_kernel<<<4096, 256, 0, stream>>>(aug, don, acc, W1t, b1, H1);

  gemm2_kernel<<<4096, 256, 0, stream>>>(H1, W2t, b2, W3, pot);

  transcript_softmax_kernel<<<NB, 64, 0, stream>>>(pot, tj, b3, refp, out);
}